// Round 21
// baseline (291.400 us; speedup 1.0000x reference)
//
#include <hip/hip_runtime.h>
#include <hip/hip_bf16.h>

// Shapes (fixed for this problem)
constexpr int B = 2, N = 512, H = 12, C = 16, PQ = 4, PV = 8, CZ = 128, CS = 384;
constexpr int HC   = H * C;            // 192
constexpr int FEAT = (CZ + C + PV * 4) * H; // 2112
constexpr float QK_SCALE  = 0.14433756729740643f;  // (3*C)^-0.5
constexpr float INV_SQRT3 = 0.5773502691896258f;
constexpr float WC_IS3    = 0.13608276348795434f;  // sqrt(2/(9*PQ))*3^-0.5

using f32x4 = __attribute__((ext_vector_type(4))) float;
using s16x8 = __attribute__((ext_vector_type(8))) short;

__device__ __forceinline__ short f2b(float f) {
    union { __hip_bfloat16 b; short s; } u;
    u.b = __float2bfloat16(f);
    return u.s;
}
__device__ __forceinline__ float b2f(short s) {
    union { short s; __hip_bfloat16 b; } u;
    u.s = s;
    return __bfloat162float(u.b);
}

// kkpS permuted layout (dense wave transactions), see round 14/16.
__device__ __forceinline__ size_t kkps_idx(int row, int col) {
    return ((size_t)((row >> 4) * 12 + (col >> 5))) * 512
         + (size_t)(((row & 15) << 2) + ((col & 31) >> 3)) * 8 + (col & 7);
}

// ---------------------------------------------------------------------------
// Kernel 1: projections + packing. RPB=2, 512 blocks. (byte-identical to r20)
// ---------------------------------------------------------------------------
constexpr int RPB = 2;

__global__ __launch_bounds__(256) void k_proj(
    const float* __restrict__ s, const float* __restrict__ rot, const float* __restrict__ trans,
    const float* __restrict__ Wq, const float* __restrict__ bq,
    const float* __restrict__ Wkv, const float* __restrict__ bkv,
    const float* __restrict__ Wqp, const float* __restrict__ bqp,
    const float* __restrict__ Wkvp, const float* __restrict__ bkvp,
    const float* __restrict__ gamma, const float* __restrict__ bb,
    const float* __restrict__ Wout,
    short* __restrict__ qcw, short* __restrict__ kkpS,
    float* __restrict__ vw, float* __restrict__ vpw,
    short* __restrict__ pcw, float* __restrict__ auxw,
    short* __restrict__ WT)
{
    __shared__ float s_s[RPB][CS];
    __shared__ float rawqp_s[RPB][144];
    __shared__ float rawkvp_s[RPB][432];
    __shared__ float qrot_s[RPB][48][3];
    __shared__ float sq_s[RPB][48];
    __shared__ float R_s[RPB][9], T_s[RPB][3];
    const int t = threadIdx.x;
    const int bi0 = blockIdx.x * RPB;

    for (int idx = t; idx < RPB * CS / 4; idx += 256) {
        int r = idx / (CS / 4), k4 = idx % (CS / 4);
        ((float4*)s_s[r])[k4] = ((const float4*)(s + (size_t)(bi0 + r) * CS))[k4];
    }
    if (t < RPB * 9) R_s[t / 9][t % 9] = rot[bi0 * 9 + t];
    if (t < RPB * 3) T_s[t / 3][t % 3] = trans[bi0 * 3 + t];
    __syncthreads();

    for (int qd = t; qd < 288; qd += 256) {
        const int c = qd * 4;
        const float* Wp; int ldw; const float* bp;
        int seg;
        if (c < 192)      { Wp = Wq   + c;        ldw = 192; bp = bq + c;        seg = 0; }
        else if (c < 576) { Wp = Wkv  + (c - 192); ldw = 384; bp = bkv + (c - 192); seg = 1; }
        else if (c < 720) { Wp = Wqp  + (c - 576); ldw = 144; bp = bqp + (c - 576); seg = 2; }
        else              { Wp = Wkvp + (c - 720); ldw = 432; bp = bkvp + (c - 720); seg = 3; }
        float4 bv = *(const float4*)bp;
        float acc[RPB][4];
        #pragma unroll
        for (int r = 0; r < RPB; ++r) {
            acc[r][0] = bv.x; acc[r][1] = bv.y; acc[r][2] = bv.z; acc[r][3] = bv.w;
        }
        for (int k4 = 0; k4 < CS / 4; ++k4) {
            float4 sv[RPB];
            #pragma unroll
            for (int r = 0; r < RPB; ++r) sv[r] = *(const float4*)&s_s[r][k4 * 4];
            #pragma unroll
            for (int e = 0; e < 4; ++e) {
                float4 wv = *(const float4*)(Wp + (size_t)(k4 * 4 + e) * ldw);
                #pragma unroll
                for (int r = 0; r < RPB; ++r) {
                    float se = ((const float*)&sv[r])[e];
                    acc[r][0] += se * wv.x; acc[r][1] += se * wv.y;
                    acc[r][2] += se * wv.z; acc[r][3] += se * wv.w;
                }
            }
        }
        if (seg == 0) {
            #pragma unroll
            for (int r = 0; r < RPB; ++r) {
                short4 o = make_short4(f2b(QK_SCALE * acc[r][0]), f2b(QK_SCALE * acc[r][1]),
                                       f2b(QK_SCALE * acc[r][2]), f2b(QK_SCALE * acc[r][3]));
                *(short4*)&qcw[(size_t)(bi0 + r) * 192 + c] = o;
            }
        } else if (seg == 1) {
            int cc = c - 192, h = cc >> 5, w5 = cc & 31;
            if (w5 < 16) {
                int col = h * 16 + w5;
                #pragma unroll
                for (int r = 0; r < RPB; ++r) {
                    short4 o = make_short4(f2b(acc[r][0]), f2b(acc[r][1]),
                                           f2b(acc[r][2]), f2b(acc[r][3]));
                    *(short4*)&kkpS[kkps_idx(bi0 + r, col)] = o;
                }
            } else {
                #pragma unroll
                for (int r = 0; r < RPB; ++r) {
                    int row = bi0 + r;
                    *(float4*)&vw[(size_t)row * 192 + h * 16 + (w5 - 16)] =
                        (float4){acc[r][0], acc[r][1], acc[r][2], acc[r][3]};
                }
            }
        } else if (seg == 2) {
            #pragma unroll
            for (int r = 0; r < RPB; ++r)
                *(float4*)&rawqp_s[r][c - 576] = (float4){acc[r][0], acc[r][1], acc[r][2], acc[r][3]};
        } else {
            #pragma unroll
            for (int r = 0; r < RPB; ++r)
                *(float4*)&rawkvp_s[r][c - 720] = (float4){acc[r][0], acc[r][1], acc[r][2], acc[r][3]};
        }
    }
    __syncthreads();

    for (int idx = t; idx < RPB * 48; idx += 256) {
        int r = idx / 48, p = idx % 48;
        float y0 = rawqp_s[r][p], y1 = rawqp_s[r][48 + p], y2 = rawqp_s[r][96 + p];
        #pragma unroll
        for (int x = 0; x < 3; ++x)
            qrot_s[r][p][x] = T_s[r][x] + R_s[r][x * 3] * y0 + R_s[r][x * 3 + 1] * y1 + R_s[r][x * 3 + 2] * y2;
    }
    for (int idx = t; idx < RPB * 144; idx += 256) {
        int r = idx / 144, p = idx % 144, h = p / 12, pp = p % 12;
        float y0 = rawkvp_s[r][p], y1 = rawkvp_s[r][144 + p], y2 = rawkvp_s[r][288 + p];
        float vals[3]; float ss = 0.0f;
        #pragma unroll
        for (int x = 0; x < 3; ++x) {
            float v = T_s[r][x] + R_s[r][x * 3] * y0 + R_s[r][x * 3 + 1] * y1 + R_s[r][x * 3 + 2] * y2;
            vals[x] = v; ss += v * v;
        }
        int row = bi0 + r;
        if (pp < PQ) {
            #pragma unroll
            for (int x = 0; x < 3; ++x)
                kkpS[kkps_idx(row, 192 + h * 16 + pp * 3 + x)] = f2b(vals[x]);
            sq_s[r][h * 4 + pp] = ss;
        } else {
            #pragma unroll
            for (int x = 0; x < 3; ++x)
                vpw[(size_t)row * 288 + h * 24 + (pp - PQ) * 3 + x] = vals[x];
        }
    }
    __syncthreads();

    if (t < RPB * 12) {
        int r = t / 12, h = t % 12, row = bi0 + r;
        float g = gamma[h];
        float sp = fmaxf(g, 0.0f) + log1pf(expf(-fabsf(g)));
        float pac = -0.5f * sp * WC_IS3;
        float kpsq = sq_s[r][h * 4] + sq_s[r][h * 4 + 1] + sq_s[r][h * 4 + 2] + sq_s[r][h * 4 + 3];
        kkpS[kkps_idx(row, 192 + h * 16 + 12)] = f2b(kpsq);
        kkpS[kkps_idx(row, 192 + h * 16 + 13)] = 0;
        kkpS[kkps_idx(row, 192 + h * 16 + 14)] = 0;
        kkpS[kkps_idx(row, 192 + h * 16 + 15)] = 0;
        float qpsq = 0.0f;
        #pragma unroll
        for (int pq = 0; pq < 4; ++pq)
            #pragma unroll
            for (int x = 0; x < 3; ++x) {
                float qv = qrot_s[r][h * 4 + pq][x];
                qpsq += qv * qv;
                pcw[(size_t)row * 192 + h * 16 + pq * 3 + x] = f2b(-2.0f * pac * qv);
            }
        pcw[(size_t)row * 192 + h * 16 + 12] = f2b(pac);
        pcw[(size_t)row * 192 + h * 16 + 13] = 0;
        pcw[(size_t)row * 192 + h * 16 + 14] = 0;
        pcw[(size_t)row * 192 + h * 16 + 15] = 0;
        auxw[(size_t)row * 16 + h] = INV_SQRT3 * bb[h] + pac * qpsq;
    }
    if (t >= RPB * 12 && t < RPB * 16) {
        int r = (t - RPB * 12) >> 2, hh = 12 + ((t - RPB * 12) & 3);
        auxw[(size_t)(bi0 + r) * 16 + hh] = 0.0f;
    }

    // ---- tail: Wout f32 [2112][384] -> WT bf16 [384][2112] ----
    short* tileb = (short*)&s_s[0][0];
    for (int tile = blockIdx.x; tile < 66 * 12; tile += 512) {
        const int k0 = (tile % 66) * 32;
        const int c0 = (tile / 66) * 32;
        __syncthreads();
        {
            int r = t >> 3, c4 = (t & 7) * 4;
            float4 v = *(const float4*)&Wout[(size_t)(k0 + r) * CS + c0 + c4];
            tileb[(c4 + 0) * 33 + r] = f2b(v.x);
            tileb[(c4 + 1) * 33 + r] = f2b(v.y);
            tileb[(c4 + 2) * 33 + r] = f2b(v.z);
            tileb[(c4 + 3) * 33 + r] = f2b(v.w);
        }
        __syncthreads();
        {
            int rr = t >> 3, k4 = (t & 7) * 4;
            short4 o = make_short4(tileb[rr * 33 + k4], tileb[rr * 33 + k4 + 1],
                                   tileb[rr * 33 + k4 + 2], tileb[rr * 33 + k4 + 3]);
            *(short4*)&WT[(size_t)(c0 + rr) * FEAT + k0 + k4] = o;
        }
    }
}

// ---------------------------------------------------------------------------
// Kernel 2a: k_logits = r20 phase 1 + merge + normalize -> Pg (bf16, global).
// Structure byte-identical to r20's phase 1 (FIFO STEP, mc_s chunk-local SM).
// ---------------------------------------------------------------------------
constexpr int PLS = 520;    // P_lds row stride (shorts)
constexpr int BSEL = 56;    // bsel row stride (shorts)

#define LOADZ(BUF, PTR)                                                  \
    {                                                                    \
        _Pragma("unroll")                                                \
        for (int k4 = 0; k4 < 4; ++k4) {                                 \
            BUF[k4 * 2]     = *(const float4*)((PTR) + k4 * 32);         \
            BUF[k4 * 2 + 1] = *(const float4*)((PTR) + k4 * 32 + 4);     \
        }                                                                \
    }

#define STEP(CUR, NXT, JC, NZPTR, KPTR)                                            \
    {                                                                              \
        s16x8 kkpf[12];                                                            \
        _Pragma("unroll")                                                          \
        for (int kk = 0; kk < 12; ++kk)                                            \
            kkpf[kk] = *(const s16x8*)((KPTR) + kk * 512);                         \
        LOADZ(NXT, NZPTR);                                                         \
        f32x4 accA = (f32x4){0, 0, 0, 0}, accB = (f32x4){0, 0, 0, 0};              \
        _Pragma("unroll")                                                          \
        for (int kk = 0; kk < 4; ++kk) {                                           \
            float4 u0 = CUR[kk * 2], u1 = CUR[kk * 2 + 1];                         \
            s16x8 f;                                                               \
            f[0] = f2b(u0.x); f[1] = f2b(u0.y); f[2] = f2b(u0.z); f[3] = f2b(u0.w);\
            f[4] = f2b(u1.x); f[5] = f2b(u1.y); f[6] = f2b(u1.z); f[7] = f2b(u1.w);\
            s16x8 wb = *(const s16x8*)(bl + kk * 8);                               \
            accA = __builtin_amdgcn_mfma_f32_16x16x32_bf16(f, wb, accA, 0, 0, 0);  \
        }                                                                          \
        s16x8 qselr = *(const s16x8*)(bl + 32);                                    \
        s16x8 pselr = *(const s16x8*)(bl + 40);                                    \
        _Pragma("unroll")                                                          \
        for (int kk = 0; kk < 6; ++kk) {                                           \
            s16x8 bsel = (kk == half) ? qselr : z8;                                \
            accB = __builtin_amdgcn_mfma_f32_16x16x32_bf16(kkpf[kk], bsel, accB, 0, 0, 0); \
        }                                                                          \
        _Pragma("unroll")                                                          \
        for (int kk = 6; kk < 12; ++kk) {                                          \
            s16x8 bsel = ((kk - 6) == half) ? pselr : z8;                          \
            accA = __builtin_amdgcn_mfma_f32_16x16x32_bf16(kkpf[kk], bsel, accA, 0, 0, 0); \
        }                                                                          \
        f32x4 acc = accA + accB;                                                   \
        float4 m4 = *(const float4*)(mkp + (JC) * 16);                             \
        float lo[4]; float cm = -INFINITY;                                         \
        _Pragma("unroll")                                                          \
        for (int r = 0; r < 4; ++r) {                                              \
            lo[r] = acc[r] + constH + 100000.0f * (mask_i * ((const float*)&m4)[r] - 1.0f); \
            cm = fmaxf(cm, lo[r]);                                                 \
        }                                                                          \
        cm = fmaxf(cm, __shfl_xor(cm, 16, 64));                                    \
        cm = fmaxf(cm, __shfl_xor(cm, 32, 64));                                    \
        float p[4]; float ps = 0.0f;                                               \
        _Pragma("unroll")                                                          \
        for (int r = 0; r < 4; ++r) { p[r] = __expf(lo[r] - cm); ps += p[r]; }     \
        ps += __shfl_xor(ps, 16, 64);                                              \
        ps += __shfl_xor(ps, 32, 64);                                              \
        float mnew = fmaxf(m_run, cm);                                             \
        float sc = __expf(m_run - mnew);                                           \
        l_run = l_run * sc + ps * __expf(cm - mnew);                               \
        m_run = mnew;                                                              \
        if (lg == 0) mc_s[w][m15][JC] = cm;                                        \
        *(short4*)&P_lds[m15 * PLS + jw + (JC) * 16 + lg * 4] =                    \
            make_short4(f2b(p[0]), f2b(p[1]), f2b(p[2]), f2b(p[3]));               \
    }

__global__ __launch_bounds__(256) void k_logits(
    const float* __restrict__ z, const float* __restrict__ seq_mask,
    const float* __restrict__ Wb,
    const short* __restrict__ qcw, const short* __restrict__ kkpS,
    const short* __restrict__ pcw, const float* __restrict__ auxw,
    short* __restrict__ Pg)
{
    __shared__ short P_lds[16 * PLS];                    // 16.6 KB
    __shared__ __align__(16) short bsel_lds[64 * BSEL];  // 7 KB
    __shared__ float ml_s[4][16], ll_s[4][16], M_s[16], Linv_s[16];
    __shared__ float mc_s[4][16][8];                     // 2 KB chunk maxima

    const int t = threadIdx.x;
    const int w   = t >> 6;          // 0..3
    const int l   = t & 63;
    const int lg  = l >> 4;
    const int m15 = l & 15;
    const int bi  = blockIdx.x;
    const int b   = bi >> 9;
    const int i   = bi & (N - 1);

    const bool hv = (m15 < 12);
    const int hcl = hv ? m15 : 0;
    const int half = m15 >> 1;
    const float constH = auxw[(size_t)bi * 16 + m15];
    const float mask_i = seq_mask[bi];

    if (w == 0) {
        short* dst = &bsel_lds[l * BSEL];
        #pragma unroll
        for (int kk = 0; kk < 4; ++kk)
            #pragma unroll
            for (int e = 0; e < 8; ++e) {
                int c = kk * 32 + lg * 8 + e;
                dst[kk * 8 + e] = f2b(hv ? INV_SQRT3 * Wb[c * H + hcl] : 0.0f);
            }
        const bool selh = ((lg >> 1) == (m15 & 1));
        const s16x8 z8v = {0, 0, 0, 0, 0, 0, 0, 0};
        const short* qrow = qcw + (size_t)bi * 192 + hcl * 16;
        s16x8 qlo = *(const s16x8*)qrow;
        s16x8 qhi = *(const s16x8*)(qrow + 8);
        s16x8 q = (hv && selh) ? ((lg & 1) ? qhi : qlo) : z8v;
        const short* prow = pcw + (size_t)bi * 192 + hcl * 16;
        s16x8 plo = *(const s16x8*)prow;
        s16x8 phi = *(const s16x8*)(prow + 8);
        s16x8 p = (hv && selh) ? ((lg & 1) ? phi : plo) : z8v;
        *(s16x8*)(dst + 32) = q;
        *(s16x8*)(dst + 40) = p;
    }
    __syncthreads();

    float m_run = -INFINITY, l_run = 0.0f;

    const size_t zbase = ((size_t)b * N + i) * (size_t)(N * CZ);
    const int jw = w * 128;
    const float* zAp = z + zbase + (size_t)(jw + m15) * CZ + lg * 8;
    const short* kAp = kkpS + ((size_t)(b * 32 + (jw >> 4))) * 6144
                            + (size_t)(m15 * 4 + lg) * 8;
    const float* mkp = seq_mask + b * N + jw + lg * 4;
    const short* bl = &bsel_lds[l * BSEL];
    const s16x8 z8 = {0, 0, 0, 0, 0, 0, 0, 0};

    float4 bufA[8], bufB[8];
    LOADZ(bufA, zAp);

    for (int jc2 = 0; jc2 < 8; jc2 += 2) {
        STEP(bufA, bufB, jc2, zAp + 16 * CZ, kAp);
        kAp += 6144;
        STEP(bufB, bufA, jc2 + 1,
             (jc2 == 6) ? (zAp + 16 * CZ) : (zAp + 32 * CZ), kAp);  // last: dead reload
        kAp += 6144;
        zAp += 32 * CZ;
    }

    if (lg == 0) { ml_s[w][m15] = m_run; ll_s[w][m15] = l_run; }
    __syncthreads();
    if (t < 16) {
        float M = ml_s[0][t];
        M = fmaxf(M, ml_s[1][t]); M = fmaxf(M, ml_s[2][t]); M = fmaxf(M, ml_s[3][t]);
        float Lt = 0.0f;
        #pragma unroll
        for (int ww = 0; ww < 4; ++ww) Lt += ll_s[ww][t] * __expf(ml_s[ww][t] - M);
        M_s[t] = M;
        Linv_s[t] = 1.0f / Lt;
    }
    __syncthreads();

    // normalize + write to Pg: thread t -> row h = t>>4, cols [(t&15)*32, +32)
    {
        const int h = t >> 4, j0t = (t & 15) * 32;
        const int wv = j0t >> 7;
        const float Li = Linv_s[h], Mh = M_s[h];
        short* dst = Pg + (size_t)bi * 8192 + h * 512 + j0t;
        #pragma unroll
        for (int k = 0; k < 4; ++k) {
            const int lc = ((j0t & 127) >> 4) + (k >> 1);   // local chunk 0..7
            const float sS = __expf(mc_s[wv][h][lc] - Mh) * Li;
            s16x8 v = *(const s16x8*)&P_lds[h * PLS + j0t + k * 8];
            s16x8 o;
            #pragma unroll
            for (int e = 0; e < 8; ++e) o[e] = f2b(b2f(v[e]) * sS);
            *(s16x8*)(dst + k * 8) = o;
        }
    }
}

// ---------------------------------------------------------------------------
// Kernel 2b: k_pv = r20 phase 2 + epilogue, reading P from Pg (global).
// ---------------------------------------------------------------------------
__global__ __launch_bounds__(256) void k_pv(
    const float* __restrict__ z, const float* __restrict__ rot, const float* __restrict__ trans,
    const short* __restrict__ Pg,
    const float* __restrict__ vw, const float* __restrict__ vpw,
    short* __restrict__ featb)
{
    __shared__ float ored_s[4 * 192];
    __shared__ float opred_s[3 * 288];
    __shared__ float op_f[288];
    __shared__ float R_s[9], T_s[3];

    const int t = threadIdx.x;
    const int w   = t >> 6;
    const int l   = t & 63;
    const int lg  = l >> 4;
    const int m15 = l & 15;
    const int bi  = blockIdx.x;
    const int b   = bi >> 9;
    const int i   = bi & (N - 1);

    if (t < 9) R_s[t] = rot[bi * 9 + t];
    if (t < 3) T_s[t] = trans[bi * 3 + t];
    __syncthreads();

    const short* Pw = Pg + (size_t)bi * 8192;
    const size_t zbase = ((size_t)b * N + i) * (size_t)(N * CZ);
    short* F = featb + (size_t)bi * FEAT;

    // ---- opair GEMM: D[h][c]; wave w owns c-tiles w*32, w*32+16 ----
    f32x4 oa0 = (f32x4){0, 0, 0, 0}, oa1 = (f32x4){0, 0, 0, 0};
    const int c0 = w * 32;
    #pragma unroll 4
    for (int kk = 0; kk < 16; ++kk) {
        s16x8 af = *(const s16x8*)(Pw + m15 * 512 + kk * 32 + lg * 8);
        const float* zb = z + zbase + (size_t)(kk * 32 + lg * 8) * CZ + c0 + m15;
        s16x8 b0f, b1f;
        #pragma unroll
        for (int e = 0; e < 8; ++e) {
            b0f[e] = f2b(zb[(size_t)e * CZ]);
            b1f[e] = f2b(zb[(size_t)e * CZ + 16]);
        }
        oa0 = __builtin_amdgcn_mfma_f32_16x16x32_bf16(af, b0f, oa0, 0, 0, 0);
        oa1 = __builtin_amdgcn_mfma_f32_16x16x32_bf16(af, b1f, oa1, 0, 0, 0);
    }
    #pragma unroll
    for (int r = 0; r < 4; ++r) {
        int h = lg * 4 + r;
        if (h < 12) {
            F[576 + h * 128 + c0 + m15]      = f2b(oa0[r]);
            F[576 + h * 128 + c0 + 16 + m15] = f2b(oa1[r]);
        }
    }

    // ---- o partials: threads 0..191, c4 = t%48, jg = t/48 ----
    if (t < 192) {
        const int c4 = t % 48, jg = t / 48;
        const int h = c4 >> 2;
        const short* Pr = Pw + h * 512 + jg * 128;
        const float* vb = vw + ((size_t)b * N + jg * 128) * 192 + c4 * 4;
        f32x4 a = (f32x4){0, 0, 0, 0};
        #pragma unroll 2
        for (int q = 0; q < 16; ++q) {
            s16x8 pv = *(const s16x8*)(Pr + q * 8);
            #pragma unroll
            for (int e = 0; e < 8; ++e) {
                float4 v4 = *(const float4*)(vb + (size_t)(q * 8 + e) * 192);
                float pj = b2f(pv[e]);
                a[0] += pj * v4.x; a[1] += pj * v4.y; a[2] += pj * v4.z; a[3] += pj * v4.w;
            }
        }
        *(f32x4*)&ored_s[jg * 192 + c4 * 4] = a;
    }

    // ---- op partials: threads 0..215, c4 = t%72, jg = t/72 ----
    if (t < 216) {
        const int c4 = t % 72, jg = t / 72;
        const int h = c4 / 6;
        const int j0g = (jg == 0) ? 0 : (jg == 1 ? 176 : 352);
        const int nq = (jg == 2) ? 20 : 22;
        const short* Pr = Pw + h * 512 + j0g;
        const float* vb = vpw + ((size_t)b * N + j0g) * 288 + c4 * 4;
        f32x4 a = (f32x4){0, 0, 0, 0};
        #pragma unroll 2
        for (int q = 0; q < nq; ++q) {
            s16x8 pv = *(const s16x8*)(Pr + q * 8);
            #pragma unroll
            for (int e = 0; e < 8; ++e) {
                float4 v4 = *(const float4*)(vb + (size_t)(q * 8 + e) * 288);
                float pj = b2f(pv[e]);
                a[0] += pj * v4.x; a[1] += pj * v4.y; a[2] += pj * v4.z; a[3] += pj * v4.w;
            }
        }
        *(f32x4*)&opred_s[jg * 288 + c4 * 4] = a;
    }
    __syncthreads();

    if (t < 192)
        F[t] = f2b(ored_s[t] + ored_s[192 + t] + ored_s[384 + t] + ored_s[576 + t]);
    if (t < 72) {
        #pragma unroll
        for (int x = 0; x < 4; ++x) {
            int rv = t * 4 + x;
            op_f[rv] = opred_s[rv] + opred_s[288 + rv] + opred_s[576 + rv];
        }
    }
    __syncthreads();

    if (t < 96) {
        float o0 = op_f[t * 3 + 0] - T_s[0];
        float o1 = op_f[t * 3 + 1] - T_s[1];
        float o2 = op_f[t * 3 + 2] - T_s[2];
        float n2 = 0.0f;
        #pragma unroll
        for (int x = 0; x < 3; ++x) {
            float rx = R_s[0 * 3 + x] * o0 + R_s[1 * 3 + x] * o1 + R_s[2 * 3 + x] * o2; // R^T
            F[HC + 96 * x + t] = f2b(rx);
            n2 += rx * rx;
        }
        F[480 + t] = f2b(fmaxf(sqrtf(n2), 1e-6f));
    }
}

// ---------------------------------------------------------------------------
// Kernel 3: bf16 MFMA GEMM out[1024,384] = featb @ WT^T + bout (f32 out).
// BM=32, BN=32, grid 384 blocks, pipelined staging. (byte-identical to r20)
// ---------------------------------------------------------------------------
__global__ __launch_bounds__(256) void k_out(
    const short* __restrict__ featb, const short* __restrict__ WT,
    const float* __restrict__ bout, float* __restrict__ out)
{
    __shared__ short A_s[32 * 40];
    __shared__ short B_s[32 * 40];
    const int t = threadIdx.x;
    const int w   = t >> 6;
    const int l   = t & 63;
    const int lg  = l >> 4;
    const int m15 = l & 15;
    const int wm = w >> 1, wn = w & 1;
    const int bm = (blockIdx.x / 12) * 32;
    const int bn = (blockIdx.x % 12) * 32;

    f32x4 acc = (f32x4){0, 0, 0, 0};

    const int sr = (t & 127) >> 2;
    const int sk = (t & 3) * 8;

    s16x8 rS;
    if (t < 128) rS = *(const s16x8*)&featb[(size_t)(bm + sr) * FEAT + sk];
    else         rS = *(const s16x8*)&WT[(size_t)(bn + sr) * FEAT + sk];

    for (int k0 = 0; k0 < FEAT; k0 += 32) {
        __syncthreads();
        if (t < 128) *(s16x8*)&A_s[sr * 40 + sk] = rS;
        else         *(s16x8*)&B_s[sr * 40 + sk] = rS;
        __syncthreads();

        const int kn = k0 + 32;
        if (kn < FEAT) {
            if (t < 128) rS = *(const s16x8*)&featb[(size_t)(bm + sr) * FEAT + kn + sk];
            else         rS = *(const s16x8*)&WT[(size_t)(bn + sr) * FEAT + kn + sk];
        }

        s16x8 af = *(const s16x8*)&A_s[(wm * 16 + m15) * 40 + lg * 8];
        s16x8 bf = *(const s16x8*)&B_s[(wn * 16 + m15) * 40 + lg * 8];
        acc = __builtin_amdgcn_mfma_f32_16x16x32_bf16(af, bf, acc, 0, 0, 0);
    }

    {
        int col = bn + wn * 16 + m15;
        float bo = bout[col];
        #pragma unroll
        for (int r = 0; r < 4; ++r) {
            int row = bm + wm * 16 + lg * 4 + r;
            out[(size_t)row * CS + col] = acc[r] + bo;
        }
    }
}

// ---------------------------------------------------------------------------
extern "C" void kernel_launch(void* const* d_in, const int* in_sizes, int n_in,
                              void* d_out, int out_size, void* d_ws, size_t ws_size,
                              hipStream_t stream)
{
    const float* s     = (const float*)d_in[0];
    const float* z     = (const float*)d_in[1];
    const float* rot   = (const float*)d_in[2];
    const float* trans = (const float*)d_in[3];
    const float* mask  = (const float*)d_in[4];
    const float* Wq    = (const float*)d_in[5];
    const float* bq    = (const float*)d_in[6];
    const float* Wkv   = (const float*)d_in[7];
    const float* bkv   = (const float*)d_in[8];
    const float* Wb    = (const float*)d_in[9];
    const float* bb    = (const float*)d_in[10];
    const float* Wqp   = (const float*)d_in[11];
    const float* bqp   = (const float*)d_in[12];
    const float* Wkvp  = (const float*)d_in[13];
    const float* bkvp  = (const float*)d_in[14];
    const float* gamma = (const float*)d_in[15];
    const float* Wout  = (const float*)d_in[16];
    const float* bout  = (const float*)d_in[17];

    // workspace layout (bytes), 16B-aligned; total 26,329,088 (= r17 proven)
    char* wsb = (char*)d_ws;
    short* featb = (short*)wsb;                      // 4,325,376
    float* vw    = (float*)(wsb + 4325376);          //   786,432
    float* vpw   = (float*)(wsb + 5111808);          // 1,179,648
    float* auxw  = (float*)(wsb + 6291456);          //    65,536
    short* qcw   = (short*)(wsb + 6356992);          //   393,216
    short* pcw   = (short*)(wsb + 6750208);          //   393,216
    short* kkpS  = (short*)(wsb + 7143424);          //   786,432 (permuted)
    short* WT    = (short*)(wsb + 7929856);          // 1,622,016
    short* Pg    = (short*)(wsb + 9551872);          // 16,777,216

    hipLaunchKernelGGL(k_proj, dim3(B * N / RPB), dim3(256), 0, stream,
                       s, rot, trans, Wq, bq, Wkv, bkv, Wqp, bqp, Wkvp, bkvp,
                       gamma, bb, Wout, qcw, kkpS, vw, vpw, pcw, auxw, WT);
    hipLaunchKernelGGL(k_logits, dim3(B * N), dim3(256), 0, stream,
                       z, mask, Wb, qcw, kkpS, pcw, auxw, Pg);
    hipLaunchKernelGGL(k_pv, dim3(B * N), dim3(256), 0, stream,
                       z, rot, trans, Pg, vw, vpw, featb);
    hipLaunchKernelGGL(k_out, dim3(384), dim3(256), 0, stream,
                       featb, WT, bout, (float*)d_out);
}

// Round 22
// 255.234 us; speedup vs baseline: 1.1417x; 1.1417x over previous
//
#include <hip/hip_runtime.h>
#include <hip/hip_bf16.h>

// Shapes (fixed for this problem)
constexpr int B = 2, N = 512, H = 12, C = 16, PQ = 4, PV = 8, CZ = 128, CS = 384;
constexpr int HC   = H * C;            // 192
constexpr int FEAT = (CZ + C + PV * 4) * H; // 2112
constexpr float QK_SCALE  = 0.14433756729740643f;  // (3*C)^-0.5
constexpr float INV_SQRT3 = 0.5773502691896258f;
constexpr float WC_IS3    = 0.13608276348795434f;  // sqrt(2/(9*PQ))*3^-0.5

using f32x4 = __attribute__((ext_vector_type(4))) float;
using s16x8 = __attribute__((ext_vector_type(8))) short;

__device__ __forceinline__ short f2b(float f) {
    union { __hip_bfloat16 b; short s; } u;
    u.b = __float2bfloat16(f);
    return u.s;
}
__device__ __forceinline__ float b2f(short s) {
    union { short s; __hip_bfloat16 b; } u;
    u.s = s;
    return __bfloat162float(u.b);
}

// kkpS permuted layout (dense wave transactions), see round 14/16.
__device__ __forceinline__ size_t kkps_idx(int row, int col) {
    return ((size_t)((row >> 4) * 12 + (col >> 5))) * 512
         + (size_t)(((row & 15) << 2) + ((col & 31) >> 3)) * 8 + (col & 7);
}

// ---------------------------------------------------------------------------
// Kernel 1: projections + packing. RPB=2, 512 blocks.
// NO unroll pragma on the K-loop — r15 scratch-demotion lesson.
// ---------------------------------------------------------------------------
constexpr int RPB = 2;

__global__ __launch_bounds__(256) void k_proj(
    const float* __restrict__ s, const float* __restrict__ rot, const float* __restrict__ trans,
    const float* __restrict__ Wq, const float* __restrict__ bq,
    const float* __restrict__ Wkv, const float* __restrict__ bkv,
    const float* __restrict__ Wqp, const float* __restrict__ bqp,
    const float* __restrict__ Wkvp, const float* __restrict__ bkvp,
    const float* __restrict__ gamma, const float* __restrict__ bb,
    const float* __restrict__ Wout,
    short* __restrict__ qcw, short* __restrict__ kkpS,
    float* __restrict__ vw, float* __restrict__ vpw,
    short* __restrict__ pcw, float* __restrict__ auxw,
    short* __restrict__ WT)
{
    __shared__ float s_s[RPB][CS];
    __shared__ float rawqp_s[RPB][144];
    __shared__ float rawkvp_s[RPB][432];
    __shared__ float qrot_s[RPB][48][3];
    __shared__ float sq_s[RPB][48];
    __shared__ float R_s[RPB][9], T_s[RPB][3];
    const int t = threadIdx.x;
    const int bi0 = blockIdx.x * RPB;

    for (int idx = t; idx < RPB * CS / 4; idx += 256) {
        int r = idx / (CS / 4), k4 = idx % (CS / 4);
        ((float4*)s_s[r])[k4] = ((const float4*)(s + (size_t)(bi0 + r) * CS))[k4];
    }
    if (t < RPB * 9) R_s[t / 9][t % 9] = rot[bi0 * 9 + t];
    if (t < RPB * 3) T_s[t / 3][t % 3] = trans[bi0 * 3 + t];
    __syncthreads();

    for (int qd = t; qd < 288; qd += 256) {
        const int c = qd * 4;
        const float* Wp; int ldw; const float* bp;
        int seg;
        if (c < 192)      { Wp = Wq   + c;        ldw = 192; bp = bq + c;        seg = 0; }
        else if (c < 576) { Wp = Wkv  + (c - 192); ldw = 384; bp = bkv + (c - 192); seg = 1; }
        else if (c < 720) { Wp = Wqp  + (c - 576); ldw = 144; bp = bqp + (c - 576); seg = 2; }
        else              { Wp = Wkvp + (c - 720); ldw = 432; bp = bkvp + (c - 720); seg = 3; }
        float4 bv = *(const float4*)bp;
        float acc[RPB][4];
        #pragma unroll
        for (int r = 0; r < RPB; ++r) {
            acc[r][0] = bv.x; acc[r][1] = bv.y; acc[r][2] = bv.z; acc[r][3] = bv.w;
        }
        for (int k4 = 0; k4 < CS / 4; ++k4) {
            float4 sv[RPB];
            #pragma unroll
            for (int r = 0; r < RPB; ++r) sv[r] = *(const float4*)&s_s[r][k4 * 4];
            #pragma unroll
            for (int e = 0; e < 4; ++e) {
                float4 wv = *(const float4*)(Wp + (size_t)(k4 * 4 + e) * ldw);
                #pragma unroll
                for (int r = 0; r < RPB; ++r) {
                    float se = ((const float*)&sv[r])[e];
                    acc[r][0] += se * wv.x; acc[r][1] += se * wv.y;
                    acc[r][2] += se * wv.z; acc[r][3] += se * wv.w;
                }
            }
        }
        if (seg == 0) {
            #pragma unroll
            for (int r = 0; r < RPB; ++r) {
                short4 o = make_short4(f2b(QK_SCALE * acc[r][0]), f2b(QK_SCALE * acc[r][1]),
                                       f2b(QK_SCALE * acc[r][2]), f2b(QK_SCALE * acc[r][3]));
                *(short4*)&qcw[(size_t)(bi0 + r) * 192 + c] = o;
            }
        } else if (seg == 1) {
            int cc = c - 192, h = cc >> 5, w5 = cc & 31;
            if (w5 < 16) {
                int col = h * 16 + w5;
                #pragma unroll
                for (int r = 0; r < RPB; ++r) {
                    short4 o = make_short4(f2b(acc[r][0]), f2b(acc[r][1]),
                                           f2b(acc[r][2]), f2b(acc[r][3]));
                    *(short4*)&kkpS[kkps_idx(bi0 + r, col)] = o;
                }
            } else {
                #pragma unroll
                for (int r = 0; r < RPB; ++r) {
                    int row = bi0 + r;
                    *(float4*)&vw[(size_t)row * 192 + h * 16 + (w5 - 16)] =
                        (float4){acc[r][0], acc[r][1], acc[r][2], acc[r][3]};
                }
            }
        } else if (seg == 2) {
            #pragma unroll
            for (int r = 0; r < RPB; ++r)
                *(float4*)&rawqp_s[r][c - 576] = (float4){acc[r][0], acc[r][1], acc[r][2], acc[r][3]};
        } else {
            #pragma unroll
            for (int r = 0; r < RPB; ++r)
                *(float4*)&rawkvp_s[r][c - 720] = (float4){acc[r][0], acc[r][1], acc[r][2], acc[r][3]};
        }
    }
    __syncthreads();

    for (int idx = t; idx < RPB * 48; idx += 256) {
        int r = idx / 48, p = idx % 48;
        float y0 = rawqp_s[r][p], y1 = rawqp_s[r][48 + p], y2 = rawqp_s[r][96 + p];
        #pragma unroll
        for (int x = 0; x < 3; ++x)
            qrot_s[r][p][x] = T_s[r][x] + R_s[r][x * 3] * y0 + R_s[r][x * 3 + 1] * y1 + R_s[r][x * 3 + 2] * y2;
    }
    for (int idx = t; idx < RPB * 144; idx += 256) {
        int r = idx / 144, p = idx % 144, h = p / 12, pp = p % 12;
        float y0 = rawkvp_s[r][p], y1 = rawkvp_s[r][144 + p], y2 = rawkvp_s[r][288 + p];
        float vals[3]; float ss = 0.0f;
        #pragma unroll
        for (int x = 0; x < 3; ++x) {
            float v = T_s[r][x] + R_s[r][x * 3] * y0 + R_s[r][x * 3 + 1] * y1 + R_s[r][x * 3 + 2] * y2;
            vals[x] = v; ss += v * v;
        }
        int row = bi0 + r;
        if (pp < PQ) {
            #pragma unroll
            for (int x = 0; x < 3; ++x)
                kkpS[kkps_idx(row, 192 + h * 16 + pp * 3 + x)] = f2b(vals[x]);
            sq_s[r][h * 4 + pp] = ss;
        } else {
            #pragma unroll
            for (int x = 0; x < 3; ++x)
                vpw[(size_t)row * 288 + h * 24 + (pp - PQ) * 3 + x] = vals[x];
        }
    }
    __syncthreads();

    if (t < RPB * 12) {
        int r = t / 12, h = t % 12, row = bi0 + r;
        float g = gamma[h];
        float sp = fmaxf(g, 0.0f) + log1pf(expf(-fabsf(g)));
        float pac = -0.5f * sp * WC_IS3;
        float kpsq = sq_s[r][h * 4] + sq_s[r][h * 4 + 1] + sq_s[r][h * 4 + 2] + sq_s[r][h * 4 + 3];
        kkpS[kkps_idx(row, 192 + h * 16 + 12)] = f2b(kpsq);
        kkpS[kkps_idx(row, 192 + h * 16 + 13)] = 0;
        kkpS[kkps_idx(row, 192 + h * 16 + 14)] = 0;
        kkpS[kkps_idx(row, 192 + h * 16 + 15)] = 0;
        float qpsq = 0.0f;
        #pragma unroll
        for (int pq = 0; pq < 4; ++pq)
            #pragma unroll
            for (int x = 0; x < 3; ++x) {
                float qv = qrot_s[r][h * 4 + pq][x];
                qpsq += qv * qv;
                pcw[(size_t)row * 192 + h * 16 + pq * 3 + x] = f2b(-2.0f * pac * qv);
            }
        pcw[(size_t)row * 192 + h * 16 + 12] = f2b(pac);
        pcw[(size_t)row * 192 + h * 16 + 13] = 0;
        pcw[(size_t)row * 192 + h * 16 + 14] = 0;
        pcw[(size_t)row * 192 + h * 16 + 15] = 0;
        auxw[(size_t)row * 16 + h] = INV_SQRT3 * bb[h] + pac * qpsq;
    }
    if (t >= RPB * 12 && t < RPB * 16) {
        int r = (t - RPB * 12) >> 2, hh = 12 + ((t - RPB * 12) & 3);
        auxw[(size_t)(bi0 + r) * 16 + hh] = 0.0f;
    }

    // ---- tail: Wout f32 [2112][384] -> WT bf16 [384][2112] ----
    short* tileb = (short*)&s_s[0][0];
    for (int tile = blockIdx.x; tile < 66 * 12; tile += 512) {
        const int k0 = (tile % 66) * 32;
        const int c0 = (tile / 66) * 32;
        __syncthreads();
        {
            int r = t >> 3, c4 = (t & 7) * 4;
            float4 v = *(const float4*)&Wout[(size_t)(k0 + r) * CS + c0 + c4];
            tileb[(c4 + 0) * 33 + r] = f2b(v.x);
            tileb[(c4 + 1) * 33 + r] = f2b(v.y);
            tileb[(c4 + 2) * 33 + r] = f2b(v.z);
            tileb[(c4 + 3) * 33 + r] = f2b(v.w);
        }
        __syncthreads();
        {
            int rr = t >> 3, k4 = (t & 7) * 4;
            short4 o = make_short4(tileb[rr * 33 + k4], tileb[rr * 33 + k4 + 1],
                                   tileb[rr * 33 + k4 + 2], tileb[rr * 33 + k4 + 3]);
            *(short4*)&WT[(size_t)(c0 + rr) * FEAT + k0 + k4] = o;
        }
    }
}

// ---------------------------------------------------------------------------
// Kernel 2: fused attention. 4 waves, wave owns 128 j (8 chunks).
// FIFO-ordered issue + chunk-local softmax (mc_s). Best-known configuration.
// ---------------------------------------------------------------------------
constexpr int PLS = 520;    // P_lds row stride (shorts)
constexpr int BSEL = 56;    // bsel row stride (shorts)

#define LOADZ(BUF, PTR)                                                  \
    {                                                                    \
        _Pragma("unroll")                                                \
        for (int k4 = 0; k4 < 4; ++k4) {                                 \
            BUF[k4 * 2]     = *(const float4*)((PTR) + k4 * 32);         \
            BUF[k4 * 2 + 1] = *(const float4*)((PTR) + k4 * 32 + 4);     \
        }                                                                \
    }

// STEP: process chunk JC using CUR z-buffer; prefetch next z into NXT.
// Issue order: kkpf (12, L2) -> LOADZ(NXT) (8, HBM) -> compute.
#define STEP(CUR, NXT, JC, NZPTR, KPTR)                                            \
    {                                                                              \
        s16x8 kkpf[12];                                                            \
        _Pragma("unroll")                                                          \
        for (int kk = 0; kk < 12; ++kk)                                            \
            kkpf[kk] = *(const s16x8*)((KPTR) + kk * 512);                         \
        LOADZ(NXT, NZPTR);                                                         \
        f32x4 accA = (f32x4){0, 0, 0, 0}, accB = (f32x4){0, 0, 0, 0};              \
        _Pragma("unroll")                                                          \
        for (int kk = 0; kk < 4; ++kk) {                                           \
            float4 u0 = CUR[kk * 2], u1 = CUR[kk * 2 + 1];                         \
            s16x8 f;                                                               \
            f[0] = f2b(u0.x); f[1] = f2b(u0.y); f[2] = f2b(u0.z); f[3] = f2b(u0.w);\
            f[4] = f2b(u1.x); f[5] = f2b(u1.y); f[6] = f2b(u1.z); f[7] = f2b(u1.w);\
            s16x8 wb = *(const s16x8*)(bl + kk * 8);                               \
            accA = __builtin_amdgcn_mfma_f32_16x16x32_bf16(f, wb, accA, 0, 0, 0);  \
        }                                                                          \
        s16x8 qselr = *(const s16x8*)(bl + 32);                                    \
        s16x8 pselr = *(const s16x8*)(bl + 40);                                    \
        _Pragma("unroll")                                                          \
        for (int kk = 0; kk < 6; ++kk) {                                           \
            s16x8 bsel = (kk == half) ? qselr : z8;                                \
            accB = __builtin_amdgcn_mfma_f32_16x16x32_bf16(kkpf[kk], bsel, accB, 0, 0, 0); \
        }                                                                          \
        _Pragma("unroll")                                                          \
        for (int kk = 6; kk < 12; ++kk) {                                          \
            s16x8 bsel = ((kk - 6) == half) ? pselr : z8;                          \
            accA = __builtin_amdgcn_mfma_f32_16x16x32_bf16(kkpf[kk], bsel, accA, 0, 0, 0); \
        }                                                                          \
        f32x4 acc = accA + accB;                                                   \
        float4 m4 = *(const float4*)(mkp + (JC) * 16);                             \
        float lo[4]; float cm = -INFINITY;                                         \
        _Pragma("unroll")                                                          \
        for (int r = 0; r < 4; ++r) {                                              \
            lo[r] = acc[r] + constH + 100000.0f * (mask_i * ((const float*)&m4)[r] - 1.0f); \
            cm = fmaxf(cm, lo[r]);                                                 \
        }                                                                          \
        cm = fmaxf(cm, __shfl_xor(cm, 16, 64));                                    \
        cm = fmaxf(cm, __shfl_xor(cm, 32, 64));                                    \
        float p[4]; float ps = 0.0f;                                               \
        _Pragma("unroll")                                                          \
        for (int r = 0; r < 4; ++r) { p[r] = __expf(lo[r] - cm); ps += p[r]; }     \
        ps += __shfl_xor(ps, 16, 64);                                              \
        ps += __shfl_xor(ps, 32, 64);                                              \
        float mnew = fmaxf(m_run, cm);                                             \
        float sc = __expf(m_run - mnew);                                           \
        l_run = l_run * sc + ps * __expf(cm - mnew);                               \
        m_run = mnew;                                                              \
        if (lg == 0) mc_s[w][m15][JC] = cm;                                        \
        *(short4*)&P_lds[m15 * PLS + jw + (JC) * 16 + lg * 4] =                    \
            make_short4(f2b(p[0]), f2b(p[1]), f2b(p[2]), f2b(p[3]));               \
    }

__global__ __launch_bounds__(256) void k_attn2(
    const float* __restrict__ z, const float* __restrict__ rot, const float* __restrict__ trans,
    const float* __restrict__ seq_mask,
    const float* __restrict__ Wb,
    const short* __restrict__ qcw, const short* __restrict__ kkpS,
    const short* __restrict__ pcw, const float* __restrict__ auxw,
    const float* __restrict__ vw, const float* __restrict__ vpw,
    short* __restrict__ featb)
{
    __shared__ short P_lds[16 * PLS];                    // 16.6 KB
    __shared__ __align__(16) char ovl[7680];             // 7.5 KB union
    short* bsel_lds = (short*)ovl;                       // [64][BSEL] phase 1
    float* ored_s   = (float*)ovl;                       // [4][192]   phase 2
    float* opred_s  = (float*)(ovl + 3072);              // [3][288]   phase 2
    float* op_f     = (float*)(ovl + 6528);              // [288]      phase 2
    __shared__ float ml_s[4][16], ll_s[4][16], M_s[16], Linv_s[16];
    __shared__ float mc_s[4][16][8];                     // 2 KB chunk maxima
    __shared__ float R_s[9], T_s[3];

    const int t = threadIdx.x;
    const int w   = t >> 6;          // 0..3
    const int l   = t & 63;
    const int lg  = l >> 4;
    const int m15 = l & 15;
    const int bi  = blockIdx.x;
    const int b   = bi >> 9;
    const int i   = bi & (N - 1);

    if (t < 9) R_s[t] = rot[bi * 9 + t];
    if (t < 3) T_s[t] = trans[bi * 3 + t];

    const bool hv = (m15 < 12);
    const int hcl = hv ? m15 : 0;
    const int half = m15 >> 1;
    const float constH = auxw[(size_t)bi * 16 + m15];
    const float mask_i = seq_mask[bi];

    if (w == 0) {
        short* dst = &bsel_lds[l * BSEL];
        #pragma unroll
        for (int kk = 0; kk < 4; ++kk)
            #pragma unroll
            for (int e = 0; e < 8; ++e) {
                int c = kk * 32 + lg * 8 + e;
                dst[kk * 8 + e] = f2b(hv ? INV_SQRT3 * Wb[c * H + hcl] : 0.0f);
            }
        const bool selh = ((lg >> 1) == (m15 & 1));
        const s16x8 z8v = {0, 0, 0, 0, 0, 0, 0, 0};
        const short* qrow = qcw + (size_t)bi * 192 + hcl * 16;
        s16x8 qlo = *(const s16x8*)qrow;
        s16x8 qhi = *(const s16x8*)(qrow + 8);
        s16x8 q = (hv && selh) ? ((lg & 1) ? qhi : qlo) : z8v;
        const short* prow = pcw + (size_t)bi * 192 + hcl * 16;
        s16x8 plo = *(const s16x8*)prow;
        s16x8 phi = *(const s16x8*)(prow + 8);
        s16x8 p = (hv && selh) ? ((lg & 1) ? phi : plo) : z8v;
        *(s16x8*)(dst + 32) = q;
        *(s16x8*)(dst + 40) = p;
    }
    __syncthreads();

    float m_run = -INFINITY, l_run = 0.0f;

    const size_t zbase = ((size_t)b * N + i) * (size_t)(N * CZ);
    const int jw = w * 128;
    const float* zAp = z + zbase + (size_t)(jw + m15) * CZ + lg * 8;
    const short* kAp = kkpS + ((size_t)(b * 32 + (jw >> 4))) * 6144
                            + (size_t)(m15 * 4 + lg) * 8;
    const float* mkp = seq_mask + b * N + jw + lg * 4;
    const short* bl = &bsel_lds[l * BSEL];
    const s16x8 z8 = {0, 0, 0, 0, 0, 0, 0, 0};

    float4 bufA[8], bufB[8];
    LOADZ(bufA, zAp);

    for (int jc2 = 0; jc2 < 8; jc2 += 2) {
        STEP(bufA, bufB, jc2, zAp + 16 * CZ, kAp);
        kAp += 6144;
        STEP(bufB, bufA, jc2 + 1,
             (jc2 == 6) ? (zAp + 16 * CZ) : (zAp + 32 * CZ), kAp);  // last: dead reload
        kAp += 6144;
        zAp += 32 * CZ;
    }

    if (lg == 0) { ml_s[w][m15] = m_run; ll_s[w][m15] = l_run; }
    __syncthreads();
    if (t < 16) {
        float M = ml_s[0][t];
        M = fmaxf(M, ml_s[1][t]); M = fmaxf(M, ml_s[2][t]); M = fmaxf(M, ml_s[3][t]);
        float Lt = 0.0f;
        #pragma unroll
        for (int ww = 0; ww < 4; ++ww) Lt += ll_s[ww][t] * __expf(ml_s[ww][t] - M);
        M_s[t] = M;
        Linv_s[t] = 1.0f / Lt;
    }
    __syncthreads();

    // normalize: thread t -> row h = t>>4, cols [(t&15)*32, +32); each
    // 8-element group lies in one 16-j chunk -> scale exp(mc - M) * Linv.
    {
        const int h = t >> 4, j0t = (t & 15) * 32;
        const int wv = j0t >> 7;
        const float Li = Linv_s[h], Mh = M_s[h];
        #pragma unroll
        for (int k = 0; k < 4; ++k) {
            const int lc = ((j0t & 127) >> 4) + (k >> 1);   // local chunk 0..7
            const float sS = __expf(mc_s[wv][h][lc] - Mh) * Li;
            s16x8 v = *(const s16x8*)&P_lds[h * PLS + j0t + k * 8];
            s16x8 o;
            #pragma unroll
            for (int e = 0; e < 8; ++e) o[e] = f2b(b2f(v[e]) * sS);
            *(s16x8*)&P_lds[h * PLS + j0t + k * 8] = o;
        }
    }
    __syncthreads();   // fences bsel reads before phase-2 overlay writes

    // ================= phase 2 =================
    short* F = featb + (size_t)bi * FEAT;

    f32x4 oa0 = (f32x4){0, 0, 0, 0}, oa1 = (f32x4){0, 0, 0, 0};
    const int c0 = w * 32;
    #pragma unroll 4
    for (int kk = 0; kk < 16; ++kk) {
        s16x8 af = *(const s16x8*)&P_lds[m15 * PLS + kk * 32 + lg * 8];
        const float* zb = z + zbase + (size_t)(kk * 32 + lg * 8) * CZ + c0 + m15;
        s16x8 b0f, b1f;
        #pragma unroll
        for (int e = 0; e < 8; ++e) {
            b0f[e] = f2b(zb[(size_t)e * CZ]);
            b1f[e] = f2b(zb[(size_t)e * CZ + 16]);
        }
        oa0 = __builtin_amdgcn_mfma_f32_16x16x32_bf16(af, b0f, oa0, 0, 0, 0);
        oa1 = __builtin_amdgcn_mfma_f32_16x16x32_bf16(af, b1f, oa1, 0, 0, 0);
    }
    #pragma unroll
    for (int r = 0; r < 4; ++r) {
        int h = lg * 4 + r;
        if (h < 12) {
            F[576 + h * 128 + c0 + m15]      = f2b(oa0[r]);
            F[576 + h * 128 + c0 + 16 + m15] = f2b(oa1[r]);
        }
    }

    if (t < 192) {
        const int c4 = t % 48, jg = t / 48;
        const int h = c4 >> 2;
        const short* Pr = &P_lds[h * PLS + jg * 128];
        const float* vb = vw + ((size_t)b * N + jg * 128) * 192 + c4 * 4;
        f32x4 a = (f32x4){0, 0, 0, 0};
        #pragma unroll 2
        for (int q = 0; q < 16; ++q) {
            s16x8 pv = *(const s16x8*)(Pr + q * 8);
            #pragma unroll
            for (int e = 0; e < 8; ++e) {
                float4 v4 = *(const float4*)(vb + (size_t)(q * 8 + e) * 192);
                float pj = b2f(pv[e]);
                a[0] += pj * v4.x; a[1] += pj * v4.y; a[2] += pj * v4.z; a[3] += pj * v4.w;
            }
        }
        *(f32x4*)&ored_s[jg * 192 + c4 * 4] = a;
    }

    if (t < 216) {
        const int c4 = t % 72, jg = t / 72;
        const int h = c4 / 6;
        const int j0g = (jg == 0) ? 0 : (jg == 1 ? 176 : 352);
        const int nq = (jg == 2) ? 20 : 22;
        const short* Pr = &P_lds[h * PLS + j0g];
        const float* vb = vpw + ((size_t)b * N + j0g) * 288 + c4 * 4;
        f32x4 a = (f32x4){0, 0, 0, 0};
        #pragma unroll 2
        for (int q = 0; q < nq; ++q) {
            s16x8 pv = *(const s16x8*)(Pr + q * 8);
            #pragma unroll
            for (int e = 0; e < 8; ++e) {
                float4 v4 = *(const float4*)(vb + (size_t)(q * 8 + e) * 288);
                float pj = b2f(pv[e]);
                a[0] += pj * v4.x; a[1] += pj * v4.y; a[2] += pj * v4.z; a[3] += pj * v4.w;
            }
        }
        *(f32x4*)&opred_s[jg * 288 + c4 * 4] = a;
    }
    __syncthreads();

    if (t < 192)
        F[t] = f2b(ored_s[t] + ored_s[192 + t] + ored_s[384 + t] + ored_s[576 + t]);
    if (t < 72) {
        #pragma unroll
        for (int x = 0; x < 4; ++x) {
            int rv = t * 4 + x;
            op_f[rv] = opred_s[rv] + opred_s[288 + rv] + opred_s[576 + rv];
        }
    }
    __syncthreads();

    if (t < 96) {
        float o0 = op_f[t * 3 + 0] - T_s[0];
        float o1 = op_f[t * 3 + 1] - T_s[1];
        float o2 = op_f[t * 3 + 2] - T_s[2];
        float n2 = 0.0f;
        #pragma unroll
        for (int x = 0; x < 3; ++x) {
            float rx = R_s[0 * 3 + x] * o0 + R_s[1 * 3 + x] * o1 + R_s[2 * 3 + x] * o2; // R^T
            F[HC + 96 * x + t] = f2b(rx);
            n2 += rx * rx;
        }
        F[480 + t] = f2b(fmaxf(sqrtf(n2), 1e-6f));
    }
}

// ---------------------------------------------------------------------------
// Kernel 3: bf16 MFMA GEMM out[1024,384] = featb @ WT^T + bout (f32 out).
// BM=32, BN=32, grid 384 blocks, pipelined staging.
// ---------------------------------------------------------------------------
__global__ __launch_bounds__(256) void k_out(
    const short* __restrict__ featb, const short* __restrict__ WT,
    const float* __restrict__ bout, float* __restrict__ out)
{
    __shared__ short A_s[32 * 40];
    __shared__ short B_s[32 * 40];
    const int t = threadIdx.x;
    const int w   = t >> 6;
    const int l   = t & 63;
    const int lg  = l >> 4;
    const int m15 = l & 15;
    const int wm = w >> 1, wn = w & 1;
    const int bm = (blockIdx.x / 12) * 32;
    const int bn = (blockIdx.x % 12) * 32;

    f32x4 acc = (f32x4){0, 0, 0, 0};

    const int sr = (t & 127) >> 2;
    const int sk = (t & 3) * 8;

    s16x8 rS;
    if (t < 128) rS = *(const s16x8*)&featb[(size_t)(bm + sr) * FEAT + sk];
    else         rS = *(const s16x8*)&WT[(size_t)(bn + sr) * FEAT + sk];

    for (int k0 = 0; k0 < FEAT; k0 += 32) {
        __syncthreads();
        if (t < 128) *(s16x8*)&A_s[sr * 40 + sk] = rS;
        else         *(s16x8*)&B_s[sr * 40 + sk] = rS;
        __syncthreads();

        const int kn = k0 + 32;
        if (kn < FEAT) {
            if (t < 128) rS = *(const s16x8*)&featb[(size_t)(bm + sr) * FEAT + kn + sk];
            else         rS = *(const s16x8*)&WT[(size_t)(bn + sr) * FEAT + kn + sk];
        }

        s16x8 af = *(const s16x8*)&A_s[(wm * 16 + m15) * 40 + lg * 8];
        s16x8 bf = *(const s16x8*)&B_s[(wn * 16 + m15) * 40 + lg * 8];
        acc = __builtin_amdgcn_mfma_f32_16x16x32_bf16(af, bf, acc, 0, 0, 0);
    }

    {
        int col = bn + wn * 16 + m15;
        float bo = bout[col];
        #pragma unroll
        for (int r = 0; r < 4; ++r) {
            int row = bm + wm * 16 + lg * 4 + r;
            out[(size_t)row * CS + col] = acc[r] + bo;
        }
    }
}

// ---------------------------------------------------------------------------
extern "C" void kernel_launch(void* const* d_in, const int* in_sizes, int n_in,
                              void* d_out, int out_size, void* d_ws, size_t ws_size,
                              hipStream_t stream)
{
    const float* s     = (const float*)d_in[0];
    const float* z     = (const float*)d_in[1];
    const float* rot   = (const float*)d_in[2];
    const float* trans = (const float*)d_in[3];
    const float* mask  = (const float*)d_in[4];
    const float* Wq    = (const float*)d_in[5];
    const float* bq    = (const float*)d_in[6];
    const float* Wkv   = (const float*)d_in[7];
    const float* bkv   = (const float*)d_in[8];
    const float* Wb    = (const float*)d_in[9];
    const float* bb    = (const float*)d_in[10];
    const float* Wqp   = (const float*)d_in[11];
    const float* bqp   = (const float*)d_in[12];
    const float* Wkvp  = (const float*)d_in[13];
    const float* bkvp  = (const float*)d_in[14];
    const float* gamma = (const float*)d_in[15];
    const float* Wout  = (const float*)d_in[16];
    const float* bout  = (const float*)d_in[17];

    // workspace layout (bytes), 16B-aligned; total 9,551,872 (< proven 12.25 MB)
    char* wsb = (char*)d_ws;
    short* featb = (short*)wsb;                      // 4,325,376
    float* vw    = (float*)(wsb + 4325376);          //   786,432
    float* vpw   = (float*)(wsb + 5111808);          // 1,179,648
    float* auxw  = (float*)(wsb + 6291456);          //    65,536
    short* qcw   = (short*)(wsb + 6356992);          //   393,216
    short* pcw   = (short*)(wsb + 6750208);          //   393,216
    short* kkpS  = (short*)(wsb + 7143424);          //   786,432 (permuted)
    short* WT    = (short*)(wsb + 7929856);          // 1,622,016

    hipLaunchKernelGGL(k_proj, dim3(B * N / RPB), dim3(256), 0, stream,
                       s, rot, trans, Wq, bq, Wkv, bkv, Wqp, bqp, Wkvp, bkvp,
                       gamma, bb, Wout, qcw, kkpS, vw, vpw, pcw, auxw, WT);
    hipLaunchKernelGGL(k_attn2, dim3(B * N), dim3(256), 0, stream,
                       z, rot, trans, mask, Wb, qcw, kkpS, pcw, auxw, vw, vpw, featb);
    hipLaunchKernelGGL(k_out, dim3(384), dim3(256), 0, stream,
                       featb, WT, bout, (float*)d_out);
}